// Round 9
// baseline (2570.175 us; speedup 1.0000x reference)
//
#include <hip/hip_runtime.h>
#include <hip/hip_fp16.h>
#include <hip/hip_bf16.h>
#include <float.h>
#include <limits.h>

// Problem constants (fixed by setup_inputs): B=16, L=256, D=128.
#define B_SZ 16
#define L_SZ 256
#define D_SZ 128

// ---------------------------------------------------------------------------
// Kernel 1: pairwise L2 distance (unchanged — not on critical path).
// ---------------------------------------------------------------------------
__global__ __launch_bounds__(256) void dist_kernel(const float* __restrict__ pred,
                                                   const float* __restrict__ target,
                                                   float* __restrict__ dist) {
    __shared__ float predRows[8][D_SZ];
    const int blk = blockIdx.x;
    const int b   = blk >> 5;
    const int i0  = (blk & 31) * 8;
    const int tid = threadIdx.x;

    for (int idx = tid; idx < 8 * D_SZ; idx += 256) {
        int r = idx >> 7, d = idx & (D_SZ - 1);
        predRows[r][d] = pred[((size_t)b * L_SZ + i0 + r) * D_SZ + d];
    }
    __syncthreads();

    const int j = tid;
    const float* tr = target + ((size_t)b * L_SZ + j) * D_SZ;
    float acc[8];
#pragma unroll
    for (int r = 0; r < 8; ++r) acc[r] = 0.0f;

    for (int d = 0; d < D_SZ; d += 4) {
        float4 tv = *(const float4*)(tr + d);
#pragma unroll
        for (int r = 0; r < 8; ++r) {
            float4 pv = *(const float4*)(&predRows[r][d]);
            float dx = pv.x - tv.x; acc[r] += dx * dx;
            float dy = pv.y - tv.y; acc[r] += dy * dy;
            float dz = pv.z - tv.z; acc[r] += dz * dz;
            float dw = pv.w - tv.w; acc[r] += dw * dw;
        }
    }
#pragma unroll
    for (int r = 0; r < 8; ++r)
        dist[((size_t)b * L_SZ + i0 + r) * L_SZ + j] = sqrtf(acc[r]);
}

// ---------------------------------------------------------------------------
// Kernel 2: JV LSA. Init: col reduction + greedy + ARR (as R5). Phases:
// MULTI-SOURCE Dijkstra (all free rows at d=0), settle until ALL free columns
// found, one dual update, then greedy vertex-disjoint path extraction from
// the shortest-path forest (tight after update) and multi-augmentation.
// One batch per block, one wave; lane t owns 0-based columns 4t..4t+3.
// ---------------------------------------------------------------------------
__device__ inline int readlane_i(int x, int l) { return __builtin_amdgcn_readlane(x, l); }
__device__ inline unsigned uminu(unsigned a, unsigned b) { return a < b ? a : b; }
template <int CTRL>
__device__ inline unsigned dpp_mov(unsigned v) {
    return (unsigned)__builtin_amdgcn_update_dpp((int)v, (int)v, CTRL, 0xF, 0xF, false);
}
// 5-step min reduce: shr1+shr2 (min3), shr3+shr6 (min3), shr9, bcast15, bcast31.
__device__ inline unsigned wave_umin_bcast(unsigned v) {
    unsigned a = dpp_mov<0x111>(v);
    unsigned b = dpp_mov<0x112>(v);
    v = uminu(uminu(v, a), b);
    a = dpp_mov<0x113>(v);
    b = dpp_mov<0x116>(v);
    v = uminu(uminu(v, a), b);
    a = dpp_mov<0x119>(v);
    v = uminu(v, a);
    a = dpp_mov<0x142>(v);
    v = uminu(v, a);
    a = dpp_mov<0x143>(v);
    v = uminu(v, a);
    return (unsigned)__builtin_amdgcn_readlane((int)v, 63);
}
__device__ inline void unpack4(uint2 pk, float& a, float& b, float& c, float& d) {
    union { unsigned u; __half2 h; } x, y; x.u = pk.x; y.u = pk.y;
    a = __low2float(x.h); b = __high2float(x.h);
    c = __low2float(y.h); d = __high2float(y.h);
}
#define SEL4(a0,a1,a2,a3,k) ((k)==0?(a0):(k)==1?(a1):(k)==2?(a2):(a3))

#define OFF_U      (L_SZ * L_SZ * 2)                 // fp16 matrix: 131072 B
#define OFF_CLAIM  (OFF_U + (L_SZ + 1) * 4)
#define OFF_FL     (OFF_CLAIM + (L_SZ + 1) * 4)
#define OFF_EP     (OFF_FL + (L_SZ + 1) * 4)
#define LSA_LDS_BYTES (OFF_EP + L_SZ * 4 + 4)        // ~135 KB (<160 KB/CU)

__global__ __launch_bounds__(64) void lsa_kernel(const float* __restrict__ dist,
                                                 double* __restrict__ partial) {
    extern __shared__ char smem[];
    float* u_lds   = (float*)(smem + OFF_U);
    int*   claimed = (int*)(smem + OFF_CLAIM);
    int*   fl      = (int*)(smem + OFF_FL);
    int*   ep      = (int*)(smem + OFF_EP);

    const int b = blockIdx.x;
    const int t = threadIdx.x;  // 0..63
    const float* cost = dist + (size_t)b * L_SZ * L_SZ;
    const int c0i = 4 * t, c1i = 4 * t + 1, c2i = 4 * t + 2, c3i = 4 * t + 3;

    // ---- stage cost as fp16 in LDS ----
    for (int idx = t * 4; idx < L_SZ * L_SZ; idx += 256) {
        float4 f = *(const float4*)(cost + idx);
        union { unsigned u; __half2 h; } a, c;
        a.h = __floats2half2_rn(f.x, f.y);
        c.h = __floats2half2_rn(f.z, f.w);
        uint2 pk; pk.x = a.u; pk.y = c.u;
        *(uint2*)(smem + idx * 2) = pk;
    }
    __syncthreads();

    // ---- column reduction: v[j] = min_i c[i][j] ----
    float bv0 = FLT_MAX, bv1 = FLT_MAX, bv2 = FLT_MAX, bv3 = FLT_MAX;
    int   br0 = 0, br1 = 0, br2 = 0, br3 = 0;
    for (int i = 1; i <= L_SZ; ++i) {
        uint2 cpk = *(const uint2*)(smem + (size_t)(i - 1) * (L_SZ * 2) + t * 8);
        float c0, c1, c2, c3; unpack4(cpk, c0, c1, c2, c3);
        if (c0 < bv0) { bv0 = c0; br0 = i; }
        if (c1 < bv1) { bv1 = c1; br1 = i; }
        if (c2 < bv2) { bv2 = c2; br2 = i; }
        if (c3 < bv3) { bv3 = c3; br3 = i; }
    }
    float v0 = bv0, v1 = bv1, v2 = bv2, v3 = bv3;

    // ---- greedy tight-edge matching via atomicMin claims ----
    for (int r = t; r <= L_SZ; r += 64) claimed[r] = INT_MAX;
    __syncthreads();
    atomicMin(&claimed[br0], c0i);
    atomicMin(&claimed[br1], c1i);
    atomicMin(&claimed[br2], c2i);
    atomicMin(&claimed[br3], c3i);
    __syncthreads();
    int p0 = (claimed[br0] == c0i) ? br0 : 0;
    int p1 = (claimed[br1] == c1i) ? br1 : 0;
    int p2 = (claimed[br2] == c2i) ? br2 : 0;
    int p3 = (claimed[br3] == c3i) ? br3 : 0;

    // ---- deterministic free-row list (ballot scan) ----
    int nf = 0;
    for (int blk = 0; blk < 4; ++blk) {
        int r = blk * 64 + t + 1;
        bool isfree = (claimed[r] == INT_MAX);
        unsigned long long mask = __ballot(isfree);
        int before = __popcll(mask & ((1ULL << t) - 1ULL));
        if (isfree) fl[nf + before] = r;
        nf += (int)__popcll(mask);
    }
    __syncthreads();

    // ---- augmenting row reduction (lap.cpp, 2 passes, budget-guarded) ----
    int numfree = nf;
    int budget = 1024;
    for (int pass = 0; pass < 2; ++pass) {
        int kq = 0, prv = numfree; numfree = 0;
        while (kq < prv && budget > 0) {
            budget--;
            int i = fl[kq]; kq++;
            uint2 cpk = *(const uint2*)(smem + (size_t)(i - 1) * (L_SZ * 2) + t * 8);
            float cc0, cc1, cc2, cc3; unpack4(cpk, cc0, cc1, cc2, cc3);
            float rc0 = cc0 - v0, rc1 = cc1 - v1, rc2 = cc2 - v2, rc3 = cc3 - v3;
            float m1 = rc0; int j1 = c0i; float m2 = FLT_MAX; int j2 = INT_MAX;
            if (rc1 < m1) { m2 = m1; j2 = j1; m1 = rc1; j1 = c1i; } else if (rc1 < m2) { m2 = rc1; j2 = c1i; }
            if (rc2 < m1) { m2 = m1; j2 = j1; m1 = rc2; j1 = c2i; } else if (rc2 < m2) { m2 = rc2; j2 = c2i; }
            if (rc3 < m1) { m2 = m1; j2 = j1; m1 = rc3; j1 = c3i; } else if (rc3 < m2) { m2 = rc3; j2 = c3i; }
#pragma unroll
            for (int off = 1; off < 64; off <<= 1) {
                float bm1 = __shfl_xor(m1, off, 64); int bj1 = __shfl_xor(j1, off, 64);
                float bm2 = __shfl_xor(m2, off, 64); int bj2 = __shfl_xor(j2, off, 64);
                bool bw = (bm1 < m1) || (bm1 == m1 && bj1 < j1);
                if (bw) {
                    if (bm2 < m1 || (bm2 == m1 && bj2 < j1)) { m2 = bm2; j2 = bj2; }
                    else { m2 = m1; j2 = j1; }
                    m1 = bm1; j1 = bj1;
                } else {
                    if (bm1 < m2 || (bm1 == m2 && bj1 < j2)) { m2 = bm1; j2 = bj1; }
                }
            }
            int t1 = j1 >> 2, k1 = j1 & 3;
            int i0 = readlane_i(SEL4(p0, p1, p2, p3, k1), t1);
            bool strict = (m1 < m2);
            int jt, i0t;
            if (strict) {
                jt = j1; i0t = i0;
                float amt = m2 - m1;
                if (t == t1) {
                    if (k1 == 0) v0 -= amt; else if (k1 == 1) v1 -= amt;
                    else if (k1 == 2) v2 -= amt; else v3 -= amt;
                }
            } else if (i0 != 0) {
                jt = j2; i0t = readlane_i(SEL4(p0, p1, p2, p3, j2 & 3), j2 >> 2);
            } else { jt = j1; i0t = 0; }
            {
                int tt = jt >> 2, kk = jt & 3;
                if (t == tt) {
                    if (kk == 0) p0 = i; else if (kk == 1) p1 = i;
                    else if (kk == 2) p2 = i; else p3 = i;
                }
            }
            if (i0t != 0) {
                if (strict) { kq--; if (t == 0) fl[kq] = i0t; }
                else        { if (t == 0) fl[numfree] = i0t; numfree++; }
            }
            __syncthreads();
        }
        if (budget <= 0) break;
    }

    // ---- init tight duals u for matched rows ----
    __syncthreads();
    for (int r = t; r <= L_SZ; r += 64) u_lds[r] = 0.0f;
    __syncthreads();
    const __half* ch = (const __half*)smem;
    if (p0) u_lds[p0] = __half2float(ch[(size_t)(p0 - 1) * L_SZ + c0i]) - v0;
    if (p1) u_lds[p1] = __half2float(ch[(size_t)(p1 - 1) * L_SZ + c1i]) - v1;
    if (p2) u_lds[p2] = __half2float(ch[(size_t)(p2 - 1) * L_SZ + c2i]) - v2;
    if (p3) u_lds[p3] = __half2float(ch[(size_t)(p3 - 1) * L_SZ + c3i]) - v3;
    __syncthreads();

    // ---- multi-source shortest-path phases ----
    const unsigned HB  = __float_as_uint(1e30f) & 0xFFFFFF00u;   // settled marker
    const unsigned hp0 = HB | (unsigned)c0i, hp1 = HB | (unsigned)c1i;
    const unsigned hp2 = HB | (unsigned)c2i, hp3 = HB | (unsigned)c3i;
    float vsh0 = v0, vsh1 = v1, vsh2 = v2, vsh3 = v3;   // relax shadow of v

    for (int phase = 0; phase < 300; ++phase) {
        // -- rebuild free-row list from p --
        for (int r = t; r <= L_SZ; r += 64) claimed[r] = 0;
        __syncthreads();
        if (p0) claimed[p0] = 1;
        if (p1) claimed[p1] = 1;
        if (p2) claimed[p2] = 1;
        if (p3) claimed[p3] = 1;
        __syncthreads();
        int nfr = 0;
        for (int blk = 0; blk < 4; ++blk) {
            int r = blk * 64 + t + 1;
            bool isfree = (claimed[r] == 0);
            unsigned long long mask = __ballot(isfree);
            int before = __popcll(mask & ((1ULL << t) - 1ULL));
            if (isfree) fl[nfr + before] = r;
            nfr += (int)__popcll(mask);
        }
        __syncthreads();
        if (nfr == 0) break;

        // -- per-phase reset --
        unsigned s0 = 0x7F7FFF00u | (unsigned)c0i;
        unsigned s1 = 0x7F7FFF00u | (unsigned)c1i;
        unsigned s2 = 0x7F7FFF00u | (unsigned)c2i;
        unsigned s3 = 0x7F7FFF00u | (unsigned)c3i;
        int w0 = -1, w1 = -1, w2 = -1, w3 = -1;          // parent col, or -(fr+1) for source
        float ds0 = 0.f, ds1 = 0.f, ds2 = 0.f, ds3 = 0.f;
        int cu = 0, ru = 0;                               // used col/row bits (4 per lane)

        // -- source pass: relax from every free row (d=0 sources) --
        for (int k = 0; k < nfr; ++k) {
            int fr = fl[k];
            uint2 cr = *(const uint2*)(smem + (size_t)(fr - 1) * (L_SZ * 2) + t * 8);
            float ufr = u_lds[fr];
            float cc0, cc1, cc2, cc3; unpack4(cr, cc0, cc1, cc2, cc3);
            float n0 = fmaxf((cc0 - vsh0) - ufr, 0.0f);
            float n1 = fmaxf((cc1 - vsh1) - ufr, 0.0f);
            float n2 = fmaxf((cc2 - vsh2) - ufr, 0.0f);
            float n3 = fmaxf((cc3 - vsh3) - ufr, 0.0f);
            unsigned np0 = (__float_as_uint(n0) & 0xFFFFFF00u) | (unsigned)c0i;
            unsigned np1 = (__float_as_uint(n1) & 0xFFFFFF00u) | (unsigned)c1i;
            unsigned np2 = (__float_as_uint(n2) & 0xFFFFFF00u) | (unsigned)c2i;
            unsigned np3 = (__float_as_uint(n3) & 0xFFFFFF00u) | (unsigned)c3i;
            int src = -(fr + 1);
            bool b0 = np0 < s0, b1 = np1 < s1, b2 = np2 < s2, b3 = np3 < s3;
            w0 = b0 ? src : w0;  s0 = b0 ? np0 : s0;
            w1 = b1 ? src : w1;  s1 = b1 ? np1 : s1;
            w2 = b2 ? src : w2;  s2 = b2 ? np2 : s2;
            w3 = b3 ? src : w3;  s3 = b3 ? np3 : s3;
        }

        // -- settle loop: until all free columns found --
        int found = 0;
        float dfin = 0.f;
        for (int it = 0; it < 2 * L_SZ + 4; ++it) {
            unsigned m01 = uminu(s0, s1), m23 = uminu(s2, s3);
            unsigned m4  = uminu(m01, m23);
            int kloc = (int)(m4 & 3u);
            int myi  = SEL4(p0, p1, p2, p3, kloc);

            const unsigned pk = wave_umin_bcast(m4);
            const int   j1    = (int)(pk & 255u);
            const int   t1    = j1 >> 2;
            const float delta = __uint_as_float(pk & 0xFFFFFF00u);
            const int   i1    = readlane_i(myi, t1);
            dfin = delta;

            // branchless settle of column j1
            bool e0 = (c0i == j1), e1 = (c1i == j1), e2 = (c2i == j1), e3 = (c3i == j1);
            vsh0 = e0 ? -1e30f : vsh0;  s0 = e0 ? hp0 : s0;  ds0 = e0 ? delta : ds0;
            vsh1 = e1 ? -1e30f : vsh1;  s1 = e1 ? hp1 : s1;  ds1 = e1 ? delta : ds1;
            vsh2 = e2 ? -1e30f : vsh2;  s2 = e2 ? hp2 : s2;  ds2 = e2 ? delta : ds2;
            vsh3 = e3 ? -1e30f : vsh3;  s3 = e3 ? hp3 : s3;  ds3 = e3 ? delta : ds3;

            if (i1 == 0) {                 // settled a FREE column: path endpoint
                if (t == 0) ep[found] = j1;
                found++;
                if (found == nfr) break;   // all free columns reached
                continue;                  // free columns relax nothing
            }

            // relax all columns from row i1 (matched row of j1)
            uint2 cur = *(const uint2*)(smem + (size_t)(i1 - 1) * (L_SZ * 2) + t * 8);
            float ui = u_lds[i1];
            float cc0, cc1, cc2, cc3; unpack4(cur, cc0, cc1, cc2, cc3);
            const float base = delta - ui;
            float n0 = fmaxf((cc0 - vsh0) + base, 0.0f);
            float n1 = fmaxf((cc1 - vsh1) + base, 0.0f);
            float n2 = fmaxf((cc2 - vsh2) + base, 0.0f);
            float n3 = fmaxf((cc3 - vsh3) + base, 0.0f);
            unsigned np0 = (__float_as_uint(n0) & 0xFFFFFF00u) | (unsigned)c0i;
            unsigned np1 = (__float_as_uint(n1) & 0xFFFFFF00u) | (unsigned)c1i;
            unsigned np2 = (__float_as_uint(n2) & 0xFFFFFF00u) | (unsigned)c2i;
            unsigned np3 = (__float_as_uint(n3) & 0xFFFFFF00u) | (unsigned)c3i;
            bool b0 = np0 < s0, b1 = np1 < s1, b2 = np2 < s2, b3 = np3 < s3;
            w0 = b0 ? j1 : w0;  s0 = b0 ? np0 : s0;
            w1 = b1 ? j1 : w1;  s1 = b1 ? np1 : s1;
            w2 = b2 ? j1 : w2;  s2 = b2 ? np2 : s2;
            w3 = b3 ? j1 : w3;  s3 = b3 ? np3 : s3;
        }
        __syncthreads();   // ep[] visible; settle loop done

        // -- dual updates (PRE-augment p; settled test: vsh sentinel) --
        // settled free columns have p==0 -> u_lds[0] is scratch (unused slot).
        if (vsh0 < -1e29f) { u_lds[p0] += dfin - ds0; v0 += ds0 - dfin; }
        if (vsh1 < -1e29f) { u_lds[p1] += dfin - ds1; v1 += ds1 - dfin; }
        if (vsh2 < -1e29f) { u_lds[p2] += dfin - ds2; v2 += ds2 - dfin; }
        if (vsh3 < -1e29f) { u_lds[p3] += dfin - ds3; v3 += ds3 - dfin; }
        for (int k = t; k < nfr; k += 64) u_lds[fl[k]] += dfin;   // all sources: d=0
        vsh0 = v0; vsh1 = v1; vsh2 = v2; vsh3 = v3;
        __syncthreads();

        // -- greedy vertex-disjoint path extraction + augmentation --
        // endpoints in increasing-d order; forest edges tight after update.
        for (int k = 0; k < found; ++k) {
            int je = ep[k];
            // walk 1: check disjointness (columns via cu bits, root row via ru)
            int j = je, root = -1; bool ok = true;
            for (int st = 0; st <= L_SZ; ++st) {
                int tj = j >> 2, kj = j & 3;
                int usebits = readlane_i(cu, tj);
                if ((usebits >> kj) & 1) { ok = false; break; }
                int wj = readlane_i(SEL4(w0, w1, w2, w3, kj), tj);
                if (wj < 0) {
                    root = -wj - 1;
                    int rl = (root - 1) >> 2, rb = (root - 1) & 3;
                    int rbits = readlane_i(ru, rl);
                    ok = !((rbits >> rb) & 1);
                    break;
                }
                j = wj;
            }
            if (!ok || root < 1) continue;
            // walk 2: augment along the path and mark used
            j = je;
            for (int st = 0; st <= L_SZ; ++st) {
                int tj = j >> 2, kj = j & 3;
                int wj = readlane_i(SEL4(w0, w1, w2, w3, kj), tj);
                int wsafe = wj < 0 ? 0 : wj;
                int pn = (wj < 0) ? root
                        : readlane_i(SEL4(p0, p1, p2, p3, wsafe & 3), wsafe >> 2);
                if (t == tj) {
                    if (kj == 0) p0 = pn; else if (kj == 1) p1 = pn;
                    else if (kj == 2) p2 = pn; else p3 = pn;
                    cu |= (1 << kj);
                }
                if (wj < 0) break;
                j = wj;
            }
            int rl = (root - 1) >> 2, rb = (root - 1) & 3;
            if (t == rl) ru |= (1 << rb);
        }
        // next phase head re-syncs before any LDS reuse
    }

    // ---- matched sum from ORIGINAL fp32 distances (index-guarded) ----
    double s = 0.0;
    s += (double)cost[(size_t)max(p0 - 1, 0) * L_SZ + c0i];
    s += (double)cost[(size_t)max(p1 - 1, 0) * L_SZ + c1i];
    s += (double)cost[(size_t)max(p2 - 1, 0) * L_SZ + c2i];
    s += (double)cost[(size_t)max(p3 - 1, 0) * L_SZ + c3i];
#pragma unroll
    for (int off = 1; off < 64; off <<= 1) s += __shfl_xor(s, off, 64);
    if (t == 0) partial[b] = s;
}

// ---------------------------------------------------------------------------
// Kernel 3: final mean
// ---------------------------------------------------------------------------
__global__ void finalize_kernel(const double* __restrict__ partial, float* __restrict__ out) {
    double s = 0.0;
    for (int b = 0; b < B_SZ; ++b) s += partial[b];
    out[0] = (float)(s / (double)(B_SZ * L_SZ));
}

extern "C" void kernel_launch(void* const* d_in, const int* in_sizes, int n_in,
                              void* d_out, int out_size, void* d_ws, size_t ws_size,
                              hipStream_t stream) {
    const float* pred   = (const float*)d_in[0];
    const float* target = (const float*)d_in[1];
    float* out = (float*)d_out;

    float*  dist    = (float*)d_ws;
    double* partial = (double*)((char*)d_ws + (size_t)B_SZ * L_SZ * L_SZ * sizeof(float));

    (void)hipFuncSetAttribute((const void*)lsa_kernel,
                              hipFuncAttributeMaxDynamicSharedMemorySize,
                              LSA_LDS_BYTES);

    dist_kernel<<<B_SZ * L_SZ / 8, 256, 0, stream>>>(pred, target, dist);
    lsa_kernel<<<B_SZ, 64, LSA_LDS_BYTES, stream>>>(dist, partial);
    finalize_kernel<<<1, 1, 0, stream>>>(partial, out);
}

// Round 10
// 2171.622 us; speedup vs baseline: 1.1835x; 1.1835x over previous
//
#include <hip/hip_runtime.h>
#include <hip/hip_fp16.h>
#include <hip/hip_bf16.h>
#include <float.h>
#include <limits.h>

// Problem constants (fixed by setup_inputs): B=16, L=256, D=128.
#define B_SZ 16
#define L_SZ 256
#define D_SZ 128

// ---------------------------------------------------------------------------
// Kernel 1: pairwise L2 distance (unchanged — not on critical path).
// ---------------------------------------------------------------------------
__global__ __launch_bounds__(256) void dist_kernel(const float* __restrict__ pred,
                                                   const float* __restrict__ target,
                                                   float* __restrict__ dist) {
    __shared__ float predRows[8][D_SZ];
    const int blk = blockIdx.x;
    const int b   = blk >> 5;
    const int i0  = (blk & 31) * 8;
    const int tid = threadIdx.x;

    for (int idx = tid; idx < 8 * D_SZ; idx += 256) {
        int r = idx >> 7, d = idx & (D_SZ - 1);
        predRows[r][d] = pred[((size_t)b * L_SZ + i0 + r) * D_SZ + d];
    }
    __syncthreads();

    const int j = tid;
    const float* tr = target + ((size_t)b * L_SZ + j) * D_SZ;
    float acc[8];
#pragma unroll
    for (int r = 0; r < 8; ++r) acc[r] = 0.0f;

    for (int d = 0; d < D_SZ; d += 4) {
        float4 tv = *(const float4*)(tr + d);
#pragma unroll
        for (int r = 0; r < 8; ++r) {
            float4 pv = *(const float4*)(&predRows[r][d]);
            float dx = pv.x - tv.x; acc[r] += dx * dx;
            float dy = pv.y - tv.y; acc[r] += dy * dy;
            float dz = pv.z - tv.z; acc[r] += dz * dz;
            float dw = pv.w - tv.w; acc[r] += dw * dw;
        }
    }
#pragma unroll
    for (int r = 0; r < 8; ++r)
        dist[((size_t)b * L_SZ + i0 + r) * L_SZ + j] = sqrtf(acc[r]);
}

// ---------------------------------------------------------------------------
// Kernel 2: JV LSA. Init: col reduction + greedy + ARR (R5/R8). Phases:
// MULTI-SOURCE Dijkstra (all free rows, d=0 via virtual super-source),
// stop at FIRST settled free column, single-path augment, dual update.
// One batch per block, one wave; lane t owns 0-based columns 4t..4t+3.
// ---------------------------------------------------------------------------
__device__ inline int readlane_i(int x, int l) { return __builtin_amdgcn_readlane(x, l); }
__device__ inline unsigned uminu(unsigned a, unsigned b) { return a < b ? a : b; }
template <int CTRL>
__device__ inline unsigned dpp_mov(unsigned v) {
    return (unsigned)__builtin_amdgcn_update_dpp((int)v, (int)v, CTRL, 0xF, 0xF, false);
}
// 5-step min reduce: shr1+shr2 (min3), shr3+shr6 (min3), shr9, bcast15, bcast31.
__device__ inline unsigned wave_umin_bcast(unsigned v) {
    unsigned a = dpp_mov<0x111>(v);
    unsigned b = dpp_mov<0x112>(v);
    v = uminu(uminu(v, a), b);
    a = dpp_mov<0x113>(v);
    b = dpp_mov<0x116>(v);
    v = uminu(uminu(v, a), b);
    a = dpp_mov<0x119>(v);
    v = uminu(v, a);
    a = dpp_mov<0x142>(v);
    v = uminu(v, a);
    a = dpp_mov<0x143>(v);
    v = uminu(v, a);
    return (unsigned)__builtin_amdgcn_readlane((int)v, 63);
}
__device__ inline void unpack4(uint2 pk, float& a, float& b, float& c, float& d) {
    union { unsigned u; __half2 h; } x, y; x.u = pk.x; y.u = pk.y;
    a = __low2float(x.h); b = __high2float(x.h);
    c = __low2float(y.h); d = __high2float(y.h);
}
#define SEL4(a0,a1,a2,a3,k) ((k)==0?(a0):(k)==1?(a1):(k)==2?(a2):(a3))

#define OFF_U      (L_SZ * L_SZ * 2)                 // fp16 matrix: 131072 B
#define OFF_CLAIM  (OFF_U + (L_SZ + 1) * 4)
#define OFF_FL     (OFF_CLAIM + (L_SZ + 1) * 4)
#define LSA_LDS_BYTES (OFF_FL + (L_SZ + 1) * 4 + 4)  // 134160

__global__ __launch_bounds__(64) void lsa_kernel(const float* __restrict__ dist,
                                                 double* __restrict__ partial) {
    extern __shared__ char smem[];
    float* u_lds   = (float*)(smem + OFF_U);
    int*   claimed = (int*)(smem + OFF_CLAIM);
    int*   fl      = (int*)(smem + OFF_FL);

    const int b = blockIdx.x;
    const int t = threadIdx.x;  // 0..63
    const float* cost = dist + (size_t)b * L_SZ * L_SZ;
    const int c0i = 4 * t, c1i = 4 * t + 1, c2i = 4 * t + 2, c3i = 4 * t + 3;

    // ---- stage cost as fp16 in LDS ----
    for (int idx = t * 4; idx < L_SZ * L_SZ; idx += 256) {
        float4 f = *(const float4*)(cost + idx);
        union { unsigned u; __half2 h; } a, c;
        a.h = __floats2half2_rn(f.x, f.y);
        c.h = __floats2half2_rn(f.z, f.w);
        uint2 pk; pk.x = a.u; pk.y = c.u;
        *(uint2*)(smem + idx * 2) = pk;
    }
    __syncthreads();

    // ---- column reduction: v[j] = min_i c[i][j] ----
    float bv0 = FLT_MAX, bv1 = FLT_MAX, bv2 = FLT_MAX, bv3 = FLT_MAX;
    int   br0 = 0, br1 = 0, br2 = 0, br3 = 0;
    for (int i = 1; i <= L_SZ; ++i) {
        uint2 cpk = *(const uint2*)(smem + (size_t)(i - 1) * (L_SZ * 2) + t * 8);
        float c0, c1, c2, c3; unpack4(cpk, c0, c1, c2, c3);
        if (c0 < bv0) { bv0 = c0; br0 = i; }
        if (c1 < bv1) { bv1 = c1; br1 = i; }
        if (c2 < bv2) { bv2 = c2; br2 = i; }
        if (c3 < bv3) { bv3 = c3; br3 = i; }
    }
    float v0 = bv0, v1 = bv1, v2 = bv2, v3 = bv3;

    // ---- greedy tight-edge matching via atomicMin claims ----
    for (int r = t; r <= L_SZ; r += 64) claimed[r] = INT_MAX;
    __syncthreads();
    atomicMin(&claimed[br0], c0i);
    atomicMin(&claimed[br1], c1i);
    atomicMin(&claimed[br2], c2i);
    atomicMin(&claimed[br3], c3i);
    __syncthreads();
    int p0 = (claimed[br0] == c0i) ? br0 : 0;
    int p1 = (claimed[br1] == c1i) ? br1 : 0;
    int p2 = (claimed[br2] == c2i) ? br2 : 0;
    int p3 = (claimed[br3] == c3i) ? br3 : 0;

    // ---- deterministic free-row list (ballot scan) ----
    int nf = 0;
    for (int blk = 0; blk < 4; ++blk) {
        int r = blk * 64 + t + 1;
        bool isfree = (claimed[r] == INT_MAX);
        unsigned long long mask = __ballot(isfree);
        int before = __popcll(mask & ((1ULL << t) - 1ULL));
        if (isfree) fl[nf + before] = r;
        nf += (int)__popcll(mask);
    }
    __syncthreads();

    // ---- augmenting row reduction (lap.cpp, 2 passes, budget-guarded) ----
    int numfree = nf;
    int budget = 1024;
    for (int pass = 0; pass < 2; ++pass) {
        int kq = 0, prv = numfree; numfree = 0;
        while (kq < prv && budget > 0) {
            budget--;
            int i = fl[kq]; kq++;
            uint2 cpk = *(const uint2*)(smem + (size_t)(i - 1) * (L_SZ * 2) + t * 8);
            float cc0, cc1, cc2, cc3; unpack4(cpk, cc0, cc1, cc2, cc3);
            float rc0 = cc0 - v0, rc1 = cc1 - v1, rc2 = cc2 - v2, rc3 = cc3 - v3;
            float m1 = rc0; int j1 = c0i; float m2 = FLT_MAX; int j2 = INT_MAX;
            if (rc1 < m1) { m2 = m1; j2 = j1; m1 = rc1; j1 = c1i; } else if (rc1 < m2) { m2 = rc1; j2 = c1i; }
            if (rc2 < m1) { m2 = m1; j2 = j1; m1 = rc2; j1 = c2i; } else if (rc2 < m2) { m2 = rc2; j2 = c2i; }
            if (rc3 < m1) { m2 = m1; j2 = j1; m1 = rc3; j1 = c3i; } else if (rc3 < m2) { m2 = rc3; j2 = c3i; }
#pragma unroll
            for (int off = 1; off < 64; off <<= 1) {
                float bm1 = __shfl_xor(m1, off, 64); int bj1 = __shfl_xor(j1, off, 64);
                float bm2 = __shfl_xor(m2, off, 64); int bj2 = __shfl_xor(j2, off, 64);
                bool bw = (bm1 < m1) || (bm1 == m1 && bj1 < j1);
                if (bw) {
                    if (bm2 < m1 || (bm2 == m1 && bj2 < j1)) { m2 = bm2; j2 = bj2; }
                    else { m2 = m1; j2 = j1; }
                    m1 = bm1; j1 = bj1;
                } else {
                    if (bm1 < m2 || (bm1 == m2 && bj1 < j2)) { m2 = bm1; j2 = bj1; }
                }
            }
            int t1 = j1 >> 2, k1 = j1 & 3;
            int i0 = readlane_i(SEL4(p0, p1, p2, p3, k1), t1);
            bool strict = (m1 < m2);
            int jt, i0t;
            if (strict) {
                jt = j1; i0t = i0;
                float amt = m2 - m1;
                if (t == t1) {
                    if (k1 == 0) v0 -= amt; else if (k1 == 1) v1 -= amt;
                    else if (k1 == 2) v2 -= amt; else v3 -= amt;
                }
            } else if (i0 != 0) {
                jt = j2; i0t = readlane_i(SEL4(p0, p1, p2, p3, j2 & 3), j2 >> 2);
            } else { jt = j1; i0t = 0; }
            {
                int tt = jt >> 2, kk = jt & 3;
                if (t == tt) {
                    if (kk == 0) p0 = i; else if (kk == 1) p1 = i;
                    else if (kk == 2) p2 = i; else p3 = i;
                }
            }
            if (i0t != 0) {
                if (strict) { kq--; if (t == 0) fl[kq] = i0t; }
                else        { if (t == 0) fl[numfree] = i0t; numfree++; }
            }
            __syncthreads();
        }
        if (budget <= 0) break;
    }

    // ---- rebuild free-row list; init tight duals u ----
    __syncthreads();
    for (int r = t; r <= L_SZ; r += 64) { claimed[r] = 0; u_lds[r] = 0.0f; }
    __syncthreads();
    if (p0) claimed[p0] = 1;
    if (p1) claimed[p1] = 1;
    if (p2) claimed[p2] = 1;
    if (p3) claimed[p3] = 1;
    __syncthreads();
    int nfr = 0;
    for (int blk = 0; blk < 4; ++blk) {
        int r = blk * 64 + t + 1;
        bool isfree = (claimed[r] == 0);
        unsigned long long mask = __ballot(isfree);
        int before = __popcll(mask & ((1ULL << t) - 1ULL));
        if (isfree) fl[nfr + before] = r;
        nfr += (int)__popcll(mask);
    }
    __syncthreads();
    const __half* ch = (const __half*)smem;
    if (p0) u_lds[p0] = __half2float(ch[(size_t)(p0 - 1) * L_SZ + c0i]) - v0;
    if (p1) u_lds[p1] = __half2float(ch[(size_t)(p1 - 1) * L_SZ + c1i]) - v1;
    if (p2) u_lds[p2] = __half2float(ch[(size_t)(p2 - 1) * L_SZ + c2i]) - v2;
    if (p3) u_lds[p3] = __half2float(ch[(size_t)(p3 - 1) * L_SZ + c3i]) - v3;
    __syncthreads();

    // ---- multi-source phases, stop at first free column ----
    const unsigned HB  = __float_as_uint(1e30f) & 0xFFFFFF00u;   // settled marker
    const unsigned hp0 = HB | (unsigned)c0i, hp1 = HB | (unsigned)c1i;
    const unsigned hp2 = HB | (unsigned)c2i, hp3 = HB | (unsigned)c3i;
    float vsh0 = v0, vsh1 = v1, vsh2 = v2, vsh3 = v3;   // relax shadow of v

    for (int phase = 0; phase <= L_SZ && nfr > 0; ++phase) {
        // free-row list cached in registers (readlane-indexable, no LDS dep)
        int flr0 = fl[t], flr1 = fl[t + 64], flr2 = fl[t + 128], flr3 = fl[t + 192];

        unsigned s0 = 0x7F7FFF00u | (unsigned)c0i;
        unsigned s1 = 0x7F7FFF00u | (unsigned)c1i;
        unsigned s2 = 0x7F7FFF00u | (unsigned)c2i;
        unsigned s3 = 0x7F7FFF00u | (unsigned)c3i;
        int w0 = -1, w1 = -1, w2 = -1, w3 = -1;   // parent col; -(fr+1) = source edge
        float ds0 = 0.f, ds1 = 0.f, ds2 = 0.f, ds3 = 0.f;

        // -- source pass: relax from every free row (d=0, independent loads) --
        for (int k = 0; k < nfr; ++k) {
            int fr = readlane_i(SEL4(flr0, flr1, flr2, flr3, k >> 6), k & 63);
            uint2 cr = *(const uint2*)(smem + (size_t)(fr - 1) * (L_SZ * 2) + t * 8);
            float ufr = u_lds[fr];
            float cc0, cc1, cc2, cc3; unpack4(cr, cc0, cc1, cc2, cc3);
            float n0 = fmaxf((cc0 - vsh0) - ufr, 0.0f);
            float n1 = fmaxf((cc1 - vsh1) - ufr, 0.0f);
            float n2 = fmaxf((cc2 - vsh2) - ufr, 0.0f);
            float n3 = fmaxf((cc3 - vsh3) - ufr, 0.0f);
            unsigned np0 = (__float_as_uint(n0) & 0xFFFFFF00u) | (unsigned)c0i;
            unsigned np1 = (__float_as_uint(n1) & 0xFFFFFF00u) | (unsigned)c1i;
            unsigned np2 = (__float_as_uint(n2) & 0xFFFFFF00u) | (unsigned)c2i;
            unsigned np3 = (__float_as_uint(n3) & 0xFFFFFF00u) | (unsigned)c3i;
            int src = -(fr + 1);
            bool b0 = np0 < s0, b1 = np1 < s1, b2 = np2 < s2, b3 = np3 < s3;
            w0 = b0 ? src : w0;  s0 = b0 ? np0 : s0;
            w1 = b1 ? src : w1;  s1 = b1 ? np1 : s1;
            w2 = b2 ? src : w2;  s2 = b2 ? np2 : s2;
            w3 = b3 ? src : w3;  s3 = b3 ? np3 : s3;
        }

        // -- settle loop: break at first free column --
        int jS = 0; float dfin = 0.f;
        for (int it = 0; it <= L_SZ; ++it) {
            unsigned m01 = uminu(s0, s1), m23 = uminu(s2, s3);
            unsigned m4  = uminu(m01, m23);
            int kloc = (int)(m4 & 3u);
            int myi  = SEL4(p0, p1, p2, p3, kloc);

            const unsigned pk = wave_umin_bcast(m4);
            const int   j1    = (int)(pk & 255u);
            const int   t1    = j1 >> 2;
            const float delta = __uint_as_float(pk & 0xFFFFFF00u);
            const int   i1    = readlane_i(myi, t1);

            if (i1 == 0 || it == L_SZ) { jS = j1; dfin = delta; break; }

            // branchless settle of column j1
            bool e0 = (c0i == j1), e1 = (c1i == j1), e2 = (c2i == j1), e3 = (c3i == j1);
            vsh0 = e0 ? -1e30f : vsh0;  s0 = e0 ? hp0 : s0;  ds0 = e0 ? delta : ds0;
            vsh1 = e1 ? -1e30f : vsh1;  s1 = e1 ? hp1 : s1;  ds1 = e1 ? delta : ds1;
            vsh2 = e2 ? -1e30f : vsh2;  s2 = e2 ? hp2 : s2;  ds2 = e2 ? delta : ds2;
            vsh3 = e3 ? -1e30f : vsh3;  s3 = e3 ? hp3 : s3;  ds3 = e3 ? delta : ds3;

            // relax all columns from row i1 (matched row of j1)
            uint2 cur = *(const uint2*)(smem + (size_t)(i1 - 1) * (L_SZ * 2) + t * 8);
            float ui = u_lds[i1];
            float cc0, cc1, cc2, cc3; unpack4(cur, cc0, cc1, cc2, cc3);
            const float base = delta - ui;
            float n0 = fmaxf((cc0 - vsh0) + base, 0.0f);
            float n1 = fmaxf((cc1 - vsh1) + base, 0.0f);
            float n2 = fmaxf((cc2 - vsh2) + base, 0.0f);
            float n3 = fmaxf((cc3 - vsh3) + base, 0.0f);
            unsigned np0 = (__float_as_uint(n0) & 0xFFFFFF00u) | (unsigned)c0i;
            unsigned np1 = (__float_as_uint(n1) & 0xFFFFFF00u) | (unsigned)c1i;
            unsigned np2 = (__float_as_uint(n2) & 0xFFFFFF00u) | (unsigned)c2i;
            unsigned np3 = (__float_as_uint(n3) & 0xFFFFFF00u) | (unsigned)c3i;
            bool b0 = np0 < s0, b1 = np1 < s1, b2 = np2 < s2, b3 = np3 < s3;
            w0 = b0 ? j1 : w0;  s0 = b0 ? np0 : s0;
            w1 = b1 ? j1 : w1;  s1 = b1 ? np1 : s1;
            w2 = b2 ? j1 : w2;  s2 = b2 ? np2 : s2;
            w3 = b3 ? j1 : w3;  s3 = b3 ? np3 : s3;
        }

        // -- dual updates (pre-augment p; settled test: vsh sentinel) --
        if (vsh0 < -1e29f) { u_lds[p0] += dfin - ds0; v0 += ds0 - dfin; }
        if (vsh1 < -1e29f) { u_lds[p1] += dfin - ds1; v1 += ds1 - dfin; }
        if (vsh2 < -1e29f) { u_lds[p2] += dfin - ds2; v2 += ds2 - dfin; }
        if (vsh3 < -1e29f) { u_lds[p3] += dfin - ds3; v3 += ds3 - dfin; }
        if (t < nfr)      u_lds[flr0] += dfin;   // all sources at d=0
        if (t + 64 < nfr) u_lds[flr1] += dfin;
        if (t + 128 < nfr) u_lds[flr2] += dfin;
        if (t + 192 < nfr) u_lds[flr3] += dfin;
        vsh0 = v0; vsh1 = v1; vsh2 = v2; vsh3 = v3;
        __syncthreads();

        // -- augment along way[]; root = source row of the path --
        int root = 0;
        int j = jS;
        for (int st = 0; st <= L_SZ; ++st) {
            int tj = j >> 2, kj = j & 3;
            int wj = readlane_i(SEL4(w0, w1, w2, w3, kj), tj);
            int wsafe = wj < 0 ? 0 : wj;
            int pn = (wj < 0) ? (-wj - 1)
                    : readlane_i(SEL4(p0, p1, p2, p3, wsafe & 3), wsafe >> 2);
            if (t == tj) {
                if (kj == 0) p0 = pn; else if (kj == 1) p1 = pn;
                else if (kj == 2) p2 = pn; else p3 = pn;
            }
            if (wj < 0) { root = -wj - 1; break; }
            j = wj;
        }

        // -- remove root from free-row list (swap with last) --
        int idx = -1;
#pragma unroll
        for (int sgi = 0; sgi < 4; ++sgi) {
            int kk = sgi * 64 + t;
            bool hit = (kk < nfr) && (SEL4(flr0, flr1, flr2, flr3, sgi) == root);
            unsigned long long m = __ballot(hit);
            if (m != 0 && idx < 0) idx = sgi * 64 + (int)__ffsll((unsigned long long)m) - 1;
        }
        if (t == 0 && idx >= 0) fl[idx] = fl[nfr - 1];
        nfr--;
        __syncthreads();
    }

    // ---- matched sum from ORIGINAL fp32 distances (index-guarded) ----
    double s = 0.0;
    s += (double)cost[(size_t)max(p0 - 1, 0) * L_SZ + c0i];
    s += (double)cost[(size_t)max(p1 - 1, 0) * L_SZ + c1i];
    s += (double)cost[(size_t)max(p2 - 1, 0) * L_SZ + c2i];
    s += (double)cost[(size_t)max(p3 - 1, 0) * L_SZ + c3i];
#pragma unroll
    for (int off = 1; off < 64; off <<= 1) s += __shfl_xor(s, off, 64);
    if (t == 0) partial[b] = s;
}

// ---------------------------------------------------------------------------
// Kernel 3: final mean
// ---------------------------------------------------------------------------
__global__ void finalize_kernel(const double* __restrict__ partial, float* __restrict__ out) {
    double s = 0.0;
    for (int b = 0; b < B_SZ; ++b) s += partial[b];
    out[0] = (float)(s / (double)(B_SZ * L_SZ));
}

extern "C" void kernel_launch(void* const* d_in, const int* in_sizes, int n_in,
                              void* d_out, int out_size, void* d_ws, size_t ws_size,
                              hipStream_t stream) {
    const float* pred   = (const float*)d_in[0];
    const float* target = (const float*)d_in[1];
    float* out = (float*)d_out;

    float*  dist    = (float*)d_ws;
    double* partial = (double*)((char*)d_ws + (size_t)B_SZ * L_SZ * L_SZ * sizeof(float));

    (void)hipFuncSetAttribute((const void*)lsa_kernel,
                              hipFuncAttributeMaxDynamicSharedMemorySize,
                              LSA_LDS_BYTES);

    dist_kernel<<<B_SZ * L_SZ / 8, 256, 0, stream>>>(pred, target, dist);
    lsa_kernel<<<B_SZ, 64, LSA_LDS_BYTES, stream>>>(dist, partial);
    finalize_kernel<<<1, 1, 0, stream>>>(partial, out);
}